// Round 7
// baseline (183.457 us; speedup 1.0000x reference)
//
#include <hip/hip_runtime.h>
#include <hip/hip_bf16.h>
#include <math.h>

#define BB 4
#define LL 8192
#define DD 512
#define HH 8
#define MM (BB*LL)      // 32768
#define NQKV 1536
#define CH 32           // K-chunks for kv partial reduction (Kc = 256)

typedef __attribute__((ext_vector_type(4))) float f32x4;
typedef __attribute__((ext_vector_type(8))) short s16x8;
typedef __attribute__((ext_vector_type(4))) short s16x4;

__device__ __forceinline__ float bf2f(short u) {
  union { unsigned int i; float f; } c;
  c.i = ((unsigned int)(unsigned short)u) << 16;
  return c.f;
}
__device__ __forceinline__ short f2bf(float f) {
  union { float f; unsigned int i; } c; c.f = f;
  unsigned int r = c.i + 0x7FFFu + ((c.i >> 16) & 1u);
  return (short)(r >> 16);
}

__device__ __forceinline__ void gload16(const void* g, void* l) {
  __builtin_amdgcn_global_load_lds(
      (const __attribute__((address_space(1))) void*)(g),
      (__attribute__((address_space(3))) void*)(l), 16, 0, 0);
}

// ---------------- conversion kernels ----------------
__global__ void conv_bf16(const float* __restrict__ in, short* __restrict__ out, int n) {
  int i = (blockIdx.x * blockDim.x + threadIdx.x) * 4;
  if (i < n) {
    float4 v = *reinterpret_cast<const float4*>(in + i);
    s16x4 o;
    o[0] = f2bf(v.x); o[1] = f2bf(v.y); o[2] = f2bf(v.z); o[3] = f2bf(v.w);
    *reinterpret_cast<s16x4*>(out + i) = o;
  }
}

// w[K][N] (row-major) -> wt[N][K] bf16
__global__ void conv_wt(const float* __restrict__ w, short* __restrict__ wt, int K, int N) {
  int idx = blockIdx.x * blockDim.x + threadIdx.x;
  if (idx < K * N) {
    int n = idx / K, k = idx - n * K;
    wt[idx] = f2bf(w[(size_t)k * N + n]);
  }
}

// ---------------- 256x256 counted-vmcnt pipelined bf16 MFMA GEMM ----------------
// C = A @ BT^T + bias.  A:[M][512], BT:[N][512] bf16.  512 thr = 8 waves (2M x 4N),
// wave tile 128x64.  BK=32 K-tiles in a 4-slot rolling LDS buffer (4 x 32 KB):
// iteration t computes tile t (slot t&3) and stages tile t+2 (slot (t+2)&3 =
// slot of t-2, whose readers finished 2 barriers ago -> race-free).  ONE barrier
// per K-tile; vmcnt(4) counted gate (tile t+1 resident), vmcnt(0) only at drain.
// BK=32 rows are 64B -> frag reads hit all 32 banks uniformly; NO swizzle needed.
// MODE 0 (qkv): n0<512: q -> phi, row-major q_b[M][512]
//               512<=n0<1024: k -> phi, per-head transpose kt[head][dh][8192]
//               n0>=1024:     v -> per-head transpose vt[head][m][8192]
// MODE 1: bias -> fp32 row-major, stride 512.
template<int MODE>
__global__ __launch_bounds__(512, 2)
void gemm256(const short* __restrict__ A, const short* __restrict__ BT,
             const float* __restrict__ bias, void* __restrict__ Cout,
             short* __restrict__ ktb, short* __restrict__ vtb)
{
  constexpr int KD = 512;
  constexpr int NT = KD / 32;          // 16 K-tiles
  __shared__ __align__(16) char lds[131072];   // 4 slots x (A 16KB | B 16KB)

  const int tid = threadIdx.x;
  const int wv = tid >> 6, lane = tid & 63;
  const int wm = wv >> 2, wn = wv & 3;         // 2 m-waves x 4 n-waves
  const int fr = lane & 15, fq = lane >> 4;

  // m-major XCD chunking: each XCD owns a contiguous m-stripe
  const int gx = gridDim.x, gy = gridDim.y;
  const int d = blockIdx.y * gx + blockIdx.x;
  const int nwg = gx * gy;
  const int lin = (d & 7) * (nwg >> 3) + (d >> 3);
  const int m0 = (lin / gy) * 256, n0 = (lin % gy) * 256;

  // staging: 4 gloads per K-tile {A rows 0-127, A 128-255, B 0-127, B 128-255}
  const int srow = tid >> 2;           // 0..127
  const int sunit = tid & 3;           // 16B unit within 32-k row
  const short* Ag = A  + (size_t)(m0 + srow) * KD + sunit * 8;
  const short* Bg = BT + (size_t)(n0 + srow) * KD + sunit * 8;
  char* ldsw = lds + wv * 1024;        // + lane*16 implicit in gload_lds

  auto stage = [&](int tn) {
    const int sb = (tn & 3) * 32768;
    const int k0 = tn * 32;
    gload16(Ag + k0,                    ldsw + sb);
    gload16(Ag + (size_t)128 * KD + k0, ldsw + sb + 8192);
    gload16(Bg + k0,                    ldsw + sb + 16384);
    gload16(Bg + (size_t)128 * KD + k0, ldsw + sb + 24576);
  };

  // prologue: tiles 0,1 in flight; gate tile 0
  stage(0); stage(1);
  asm volatile("s_waitcnt vmcnt(4)" ::: "memory");
  __syncthreads();

  f32x4 acc[8][4] = {};

  for (int t = 0; t < NT; ++t) {
    const int sb = (t & 3) * 32768;
    if (t + 2 < NT) stage(t + 2);
    const char* pa = lds + sb + (wm * 128 + fr) * 64 + fq * 16;
    const char* pb = lds + sb + 16384 + (wn * 64 + fr) * 64 + fq * 16;
    s16x8 bfr[4];
#pragma unroll
    for (int j = 0; j < 4; ++j) bfr[j] = *(const s16x8*)(pb + j * 1024);
    __builtin_amdgcn_s_setprio(1);
#pragma unroll
    for (int i = 0; i < 8; ++i) {
      s16x8 af = *(const s16x8*)(pa + i * 1024);
#pragma unroll
      for (int j = 0; j < 4; ++j)
        acc[i][j] = __builtin_amdgcn_mfma_f32_16x16x32_bf16(af, bfr[j], acc[i][j], 0, 0, 0);
    }
    __builtin_amdgcn_s_setprio(0);
    if (t < NT - 2)       asm volatile("s_waitcnt vmcnt(4)" ::: "memory");
    else if (t == NT - 2) asm volatile("s_waitcnt vmcnt(0)" ::: "memory");
    __syncthreads();
  }

  // ---- epilogue (C/D layout: col = lane&15, row = (lane>>4)*4 + reg) ----
  if (MODE == 0) {
    if (n0 < 512) {
      // q: phi -> scr[256][256] bf16 (128KB), coalesced 16B stores
      short* scr = (short*)lds;
#pragma unroll
      for (int j = 0; j < 4; ++j) {
        const int col = wn * 64 + j * 16 + fr;
        const float bv = bias[n0 + col];
#pragma unroll
        for (int i = 0; i < 8; ++i) {
          const int row = wm * 128 + i * 16 + fq * 4;
#pragma unroll
          for (int r = 0; r < 4; ++r) {
            float v = acc[i][j][r] + bv;
            v = (v > 0.f) ? (v + 1.f) : __expf(v);   // phi = elu+1
            scr[(row + r) * 256 + col] = f2bf(v);
          }
        }
      }
      __syncthreads();
#pragma unroll
      for (int p = 0; p < 16; ++p) {
        const int off = p * 8192 + tid * 16;          // bytes
        const int row = off >> 9, colb = off & 511;   // 512B per row
        s16x8 v = *(const s16x8*)(lds + off);
        *(s16x8*)((short*)Cout + (size_t)(m0 + row) * 512 + n0 + (colb >> 1)) = v;
      }
    } else {
      // k/v: (phi for k) + per-head transposed write via scr_t[col][l]
      const bool do_phi = (n0 < 1024);
      short* tdst = do_phi ? ktb : vtb;
      const int f0 = n0 - (do_phi ? 512 : 1024);
#pragma unroll
      for (int j = 0; j < 4; ++j) {
        const int col = wn * 64 + j * 16 + fr;
        const float bv = bias[n0 + col];
        const int cx = col & 31;
#pragma unroll
        for (int i = 0; i < 8; ++i) {
          const int l = wm * 128 + i * 16 + fq * 4;
          s16x4 pk;
#pragma unroll
          for (int r = 0; r < 4; ++r) {
            float v = acc[i][j][r] + bv;
            if (do_phi) v = (v > 0.f) ? (v + 1.f) : __expf(v);
            pk[r] = f2bf(v);
          }
          *(s16x4*)(lds + col * 512 + (((l >> 3) ^ cx) * 16) + (l & 7) * 2) = pk;
        }
      }
      __syncthreads();
#pragma unroll
      for (int p = 0; p < 16; ++p) {
        const int g = p * 512 + tid;
        const int col = g >> 5, up = g & 31;
        const int u = up ^ (col & 31);
        s16x8 v = *(const s16x8*)(lds + col * 512 + up * 16);
        const int f = f0 + col;
        const int hb = ((m0 >> 13) << 3) + (f >> 6);
        short* dst = tdst + ((size_t)hb * 64 + (f & 63)) * 8192 + (m0 & 8191) + u * 8;
        *(s16x8*)dst = v;
      }
    }
  } else {
    // fp32 out, two row-halves through 128KB scratch
    float* scrf = (float*)lds;
#pragma unroll
    for (int h = 0; h < 2; ++h) {
      __syncthreads();
      if (wm == h) {
#pragma unroll
        for (int j = 0; j < 4; ++j) {
          const int col = wn * 64 + j * 16 + fr;
          const float bv = bias[n0 + col];
#pragma unroll
          for (int i = 0; i < 8; ++i) {
            const int row = i * 16 + fq * 4;
#pragma unroll
            for (int r = 0; r < 4; ++r)
              scrf[(row + r) * 256 + col] = acc[i][j][r] + bv;
          }
        }
      }
      __syncthreads();
#pragma unroll
      for (int p = 0; p < 16; ++p) {
        const int off = p * 8192 + tid * 16;
        const int row = off >> 10, colb = off & 1023;   // 1KB per row
        float4 v = *(const float4*)(lds + off);
        *(float4*)((float*)Cout + (size_t)(m0 + h * 128 + row) * 512 + n0 + (colb >> 2)) = v;
      }
    }
  }
}

// ---------------- kv partials via MFMA ----------------
__global__ __launch_bounds__(256, 4)
void kv_mfma(const short* __restrict__ kt, const short* __restrict__ vt,
             float* __restrict__ pkv, float* __restrict__ pks)
{
  const int hb = blockIdx.x, c = blockIdx.y;
  const int tid = threadIdx.x, wv = tid >> 6, lane = tid & 63;
  const int fr = lane & 15, fq = lane >> 4;
  const size_t base = (size_t)hb * 64 * 8192;
  const int l0 = c * 256;
  const short* vrow = vt + base + (size_t)fr * 8192 + l0 + fq * 8;
  const short* krow = kt + base + (size_t)(wv * 16 + fr) * 8192 + l0 + fq * 8;

  s16x8 ones;
#pragma unroll
  for (int j = 0; j < 8; ++j) ones[j] = (short)0x3F80;   // bf16 1.0

  f32x4 acc[4] = {};
  f32x4 accd = {};
#pragma unroll
  for (int ks = 0; ks < 8; ++ks) {
    s16x8 bfr = *(const s16x8*)(krow + ks * 32);
    accd = __builtin_amdgcn_mfma_f32_16x16x32_bf16(ones, bfr, accd, 0, 0, 0);
#pragma unroll
    for (int i = 0; i < 4; ++i) {
      s16x8 af = *(const s16x8*)(vrow + (size_t)(i * 16) * 8192 + ks * 32);
      acc[i] = __builtin_amdgcn_mfma_f32_16x16x32_bf16(af, bfr, acc[i], 0, 0, 0);
    }
  }
  float* o = pkv + ((size_t)hb * CH + c) * 4096;
#pragma unroll
  for (int i = 0; i < 4; ++i)
#pragma unroll
    for (int r = 0; r < 4; ++r)
      o[(i * 16 + fq * 4 + r) * 64 + wv * 16 + fr] = acc[i][r];
  if (fq == 0)
    pks[((size_t)hb * CH + c) * 64 + wv * 16 + fr] = accd[0];
}

// reduce partials -> bf16 kv_b [head][m][d], bf16 ksum_b [head][d] (with +1e-6)
__global__ void kv_reduce(const float* __restrict__ pkv, const float* __restrict__ pks,
                          short* __restrict__ kv_b, short* __restrict__ ksum_b)
{
  const int idx = blockIdx.x * 256 + threadIdx.x;   // head*4096 + m*64 + d
  const int head = idx >> 12, md = idx & 4095;
  float s = 0.f;
  for (int i = 0; i < CH; ++i) s += pkv[((size_t)head * CH + i) * 4096 + md];
  kv_b[idx] = f2bf(s);
  if (md < 64) {
    float t = 0.f;
    for (int i = 0; i < CH; ++i) t += pks[((size_t)head * CH + i) * 64 + md];
    ksum_b[head * 64 + md] = f2bf(t + 1e-6f);
  }
}

// ---------------- attn via MFMA: attn[l][m] = (q_l . kv[m]) / (q_l . ksum) ----------------
__global__ __launch_bounds__(256, 2)
void attn_mfma(const short* __restrict__ q_b, const short* __restrict__ kv_b,
               const short* __restrict__ ksum_b, short* __restrict__ attn)
{
  const int hb = blockIdx.x;     // 0..31 (b*H + h)
  const int tile = blockIdx.y;   // 0..31 (256 rows each)
  const int b = hb >> 3, h = hb & 7;
  const int tid = threadIdx.x, wv = tid >> 6, lane = tid & 63;
  const int fr = lane & 15, fk = (lane >> 4) * 8;

  const short* kvp = kv_b + (size_t)hb * 4096;
  s16x8 bfrag[4][2];
#pragma unroll
  for (int j = 0; j < 4; ++j)
#pragma unroll
    for (int kk = 0; kk < 2; ++kk)
      bfrag[j][kk] = *(const s16x8*)(kvp + (j * 16 + fr) * 64 + kk * 32 + fk);
  s16x8 bden[2];
#pragma unroll
  for (int kk = 0; kk < 2; ++kk)
    bden[kk] = *(const s16x8*)(ksum_b + hb * 64 + kk * 32 + fk);

  const short* qb = q_b + (size_t)b * LL * DD + h * 64;
  const int l0 = tile * 256 + wv * 64;
  f32x4 accn[4][4] = {};
  f32x4 accd[4] = {};
#pragma unroll
  for (int i = 0; i < 4; ++i) {
#pragma unroll
    for (int kk = 0; kk < 2; ++kk) {
      s16x8 a = *(const s16x8*)(qb + (size_t)(l0 + i * 16 + fr) * DD + kk * 32 + fk);
      accd[i] = __builtin_amdgcn_mfma_f32_16x16x32_bf16(a, bden[kk], accd[i], 0, 0, 0);
#pragma unroll
      for (int j = 0; j < 4; ++j)
        accn[i][j] = __builtin_amdgcn_mfma_f32_16x16x32_bf16(a, bfrag[j][kk], accn[i][j], 0, 0, 0);
    }
  }

  short* ob = attn + (size_t)b * LL * DD + h * 64;
  const int fq = lane >> 4;
#pragma unroll
  for (int i = 0; i < 4; ++i) {
#pragma unroll
    for (int r = 0; r < 4; ++r) {
      const int row = l0 + i * 16 + fq * 4 + r;
      const float dinv = 1.0f / accd[i][r];
#pragma unroll
      for (int j = 0; j < 4; ++j) {
        ob[(size_t)row * DD + j * 16 + fr] = f2bf(accn[i][j][r] * dinv);
      }
    }
  }
}

// ---------------- launch ----------------
extern "C" void kernel_launch(void* const* d_in, const int* in_sizes, int n_in,
                              void* d_out, int out_size, void* d_ws, size_t ws_size,
                              hipStream_t stream)
{
  const float* x     = (const float*)d_in[0];
  const float* w_qkv = (const float*)d_in[1];
  const float* b_qkv = (const float*)d_in[2];
  const float* w_out = (const float*)d_in[3];
  const float* b_out = (const float*)d_in[4];

  char* ws = (char*)d_ws;
  size_t off = 0;
  short* x_b   = (short*)(ws + off); off += (size_t)MM * DD * 2;        // 32 MB
  short* wq_t  = (short*)(ws + off); off += (size_t)NQKV * DD * 2;      // 1.5 MB
  short* wo_t  = (short*)(ws + off); off += (size_t)DD * DD * 2;        // 0.5 MB
  short* q_b   = (short*)(ws + off); off += (size_t)MM * DD * 2;        // 32 MB
  short* kt    = (short*)(ws + off); off += (size_t)32 * 64 * LL * 2;   // 32 MB
  short* vt    = (short*)(ws + off); off += (size_t)32 * 64 * LL * 2;   // 32 MB
  short* attn_b= (short*)(ws + off); off += (size_t)MM * DD * 2;        // 32 MB
  float* pkv   = (float*)(ws + off); off += (size_t)32 * CH * 4096 * 4; // 16 MB
  float* pks   = (float*)(ws + off); off += (size_t)32 * CH * 64 * 4;   // 0.25 MB
  short* kv_b  = (short*)(ws + off); off += (size_t)32 * 4096 * 2;      // 0.25 MB
  short* ksum_b= (short*)(ws + off); off += (size_t)32 * 64 * 2;        // 4 KB

  conv_bf16<<<dim3((MM * DD / 4 + 255) / 256), dim3(256), 0, stream>>>(x, x_b, MM * DD);
  conv_wt<<<dim3((DD * NQKV + 255) / 256), dim3(256), 0, stream>>>(w_qkv, wq_t, DD, NQKV);
  conv_wt<<<dim3((DD * DD + 255) / 256), dim3(256), 0, stream>>>(w_out, wo_t, DD, DD);

  // qkv GEMM: q -> q_b (phi), k -> kt (phi, transposed), v -> vt (transposed)
  gemm256<0><<<dim3(MM / 256, NQKV / 256), dim3(512), 0, stream>>>(
      x_b, wq_t, b_qkv, (void*)q_b, kt, vt);

  kv_mfma<<<dim3(32, CH), dim3(256), 0, stream>>>(kt, vt, pkv, pks);
  kv_reduce<<<dim3(512), dim3(256), 0, stream>>>(pkv, pks, kv_b, ksum_b);

  attn_mfma<<<dim3(32, 32), dim3(256), 0, stream>>>(q_b, kv_b, ksum_b, attn_b);

  // out = attn @ w_out + b_out (fp32)
  gemm256<1><<<dim3(MM / 256, DD / 256), dim3(512), 0, stream>>>(
      attn_b, wo_t, b_out, d_out, nullptr, nullptr);
}